// Round 1
// baseline (378.790 us; speedup 1.0000x reference)
//
#include <hip/hip_runtime.h>
#include <stdint.h>
#include <math.h>

// RPN proposal filtering: decode -> clip -> validity mask -> stable top-2000
// -> greedy NMS (IoU > 0.7) -> first 1000 kept -> (B, 1000, 5).
//
// R7: k_scanout critical-path fix. Old per-kept-row chain had TWO dependent
// v_readlane roundtrips (removed->curw re-broadcast + score readlane),
// ~109 cyc/row. New: per 16-row group, broadcast each row's current-chunk
// mask word ONCE up-front (independent readlanes -> SGPRs), and replace the
// per-row score readlane with one __ballot per 64-row chunk. Serial chain per
// row is now a uniform bit-test + s_or. curw |= bmw[j] is algebraically
// identical to the old readlane(removed|m[j], chunk).

#define IMGF 1024.0f
#define PRE_NMS 2000
#define POST_NMS 1000
#define NMS_THR 0.7f
#define MIN_SZ 16.0f
#define CAP 4096          // candidate buffer per batch
#define SEL 2048          // padded selection stride (>= PRE_NMS)
#define NW (SEL / 64)     // 32 mask words per row
#define CNT_STRIDE 32     // u32s per batch for counters (128 B -> own line)
#define KEY_NEGINF 0x007FFFFFu  // f2key(-inf)
#define MAXCHUNK 12

// Order-preserving float -> u32 key (all floats incl. -inf totally ordered).
__device__ __forceinline__ uint32_t f2key(float f) {
  uint32_t u = __float_as_uint(f);
  return (u & 0x80000000u) ? ~u : (u | 0x80000000u);
}
__device__ __forceinline__ float key2f(uint32_t k) {
  uint32_t u = (k & 0x80000000u) ? (k & 0x7FFFFFFFu) : ~k;
  return __uint_as_float(u);
}

__device__ __forceinline__ unsigned long long readlane_u64(unsigned long long v,
                                                           int lane) {
  unsigned int lo = __builtin_amdgcn_readlane((unsigned int)v, lane);
  unsigned int hi = __builtin_amdgcn_readlane((unsigned int)(v >> 32), lane);
  return ((unsigned long long)hi << 32) | lo;
}

// Mirrors reference _decode + clip, fp32.
__device__ __forceinline__ float4 decode_clip(float4 anc, float4 dlt) {
  float aw = anc.z - anc.x;
  float ah = anc.w - anc.y;
  float ax = anc.x + 0.5f * aw;
  float ay = anc.y + 0.5f * ah;
  float dw = fminf(dlt.z, 4.0f);
  float dh = fminf(dlt.w, 4.0f);
  float px = dlt.x * aw + ax;
  float py = dlt.y * ah + ay;
  float pw = expf(dw) * aw;
  float ph = expf(dh) * ah;
  float x1 = px - 0.5f * pw, y1 = py - 0.5f * ph;
  float x2 = px + 0.5f * pw, y2 = py + 0.5f * ph;
  x1 = fminf(fmaxf(x1, 0.0f), IMGF);
  y1 = fminf(fmaxf(y1, 0.0f), IMGF);
  x2 = fminf(fmaxf(x2, 0.0f), IMGF);
  y2 = fminf(fmaxf(y2, 0.0f), IMGF);
  return make_float4(x1, y1, x2, y2);
}

// K1: decode -> masked-score key; per-block LDS coarse hist of key>>24
// (finite keys only), ballot-match wave aggregation, one aggregated global
// flush per block. grid = (bpb, B).
__global__ void k_decode(const float4* __restrict__ anchors,
                         const float4* __restrict__ deltas,
                         const float* __restrict__ scores,
                         uint32_t* __restrict__ keys,
                         uint32_t* __restrict__ chist,
                         int A, int chunks) {
  int b = blockIdx.y;
  int t = threadIdx.x;  // 256
  int lane = t & 63;
  __shared__ uint32_t shist[256];
  shist[t] = 0;
  __syncthreads();
  int base_a = blockIdx.x * (chunks * 256);
  for (int c = 0; c < chunks; c++) {
    int a = base_a + c * 256 + t;
    bool inb = a < A;
    int ac = inb ? a : (A - 1);
    size_t i = (size_t)b * A + ac;
    float4 box = decode_clip(anchors[ac], deltas[i]);
    bool valid = (box.z - box.x >= MIN_SZ) && (box.w - box.y >= MIN_SZ);
    float ms = valid ? scores[i] : -INFINITY;
    uint32_t k = f2key(ms);
    if (inb) keys[i] = k;
    uint32_t bucket = k >> 24;
    bool fin = inb && (k != KEY_NEGINF);
    // lanes with equal bucket -> one LDS atomic by the leader
    unsigned long long match = __ballot(fin);
#pragma unroll
    for (int bit = 0; bit < 8; bit++) {
      bool hb = (bucket >> bit) & 1;
      unsigned long long bb = __ballot(hb && fin);
      match &= hb ? bb : ~bb;
    }
    if (fin && (__ffsll((long long)match) - 1 == lane))
      atomicAdd(&shist[bucket], (uint32_t)__popcll(match));
  }
  __syncthreads();
  uint32_t v = shist[t];
  if (v) atomicAdd(&chist[b * 256 + t], v);
}

// K2: pick coarse bucket cb s.t. countAbove(cb) < PRE_NMS <= countAbove(cb)+chist[cb].
__global__ void k_coarse(const uint32_t* __restrict__ chist,
                         int* __restrict__ cbArr,
                         uint32_t* __restrict__ cumArr) {
  int b = blockIdx.x;
  int t = threadIdx.x;  // 256
  __shared__ uint32_t sA[256];
  sA[t] = chist[b * 256 + t];
  for (int d = 1; d < 256; d <<= 1) {  // inclusive suffix scan
    __syncthreads();
    uint32_t v = sA[t] + ((t + d < 256) ? sA[t + d] : 0u);
    __syncthreads();
    sA[t] = v;
  }
  __syncthreads();
  if (t == 0 && sA[0] < PRE_NMS) {  // degenerate: < PRE_NMS finite entries
    cbArr[b] = -1;
    cumArr[b] = 0;
  }
  uint32_t nxt = (t < 255) ? sA[t + 1] : 0u;
  if (sA[t] >= PRE_NMS && nxt < PRE_NMS) {
    cbArr[b] = t;
    cumArr[b] = nxt;  // count strictly above coarse bucket t
  }
}

// K3: fine hist of key bits[23:16] for elements whose coarse bucket == cb[b].
__global__ void k_fine(const uint32_t* __restrict__ keys,
                       const int* __restrict__ cbArr,
                       uint32_t* __restrict__ fhist,
                       int A, int chunks) {
  int b = blockIdx.y;
  int t = threadIdx.x;  // 256
  int cb = cbArr[b];
  if (cb < 0) return;
  __shared__ uint32_t shist[256];
  shist[t] = 0;
  __syncthreads();
  int base_a = blockIdx.x * (chunks * 256);
  uint32_t cbu = (uint32_t)cb;
  for (int c = 0; c < chunks; c++) {
    int a = base_a + c * 256 + t;
    if (a >= A) break;
    uint32_t k = keys[(size_t)b * A + a];
    if ((k >> 24) == cbu && k != KEY_NEGINF)
      atomicAdd(&shist[(k >> 16) & 0xFFu], 1u);
  }
  __syncthreads();
  uint32_t v = shist[t];
  if (v) atomicAdd(&fhist[b * 256 + t], v);
}

// K4: final 16-bit threshold beta = (cb<<8)|d:
// count(key>>16 > beta) < PRE_NMS <= count(key>>16 >= beta), finite keys only.
__global__ void k_thresh(const uint32_t* __restrict__ fhist,
                         const int* __restrict__ cbArr,
                         const uint32_t* __restrict__ cumArr,
                         uint32_t* __restrict__ thresh,
                         uint32_t* __restrict__ cnts) {
  int b = blockIdx.x;
  int t = threadIdx.x;  // 256
  __shared__ uint32_t sA[256];
  if (t < 2) cnts[b * CNT_STRIDE + t] = 0;
  int cb = cbArr[b];
  if (cb < 0) {
    if (t == 0) thresh[b] = 0u;
    return;
  }
  uint32_t cumAbove = cumArr[b];
  sA[t] = fhist[b * 256 + t];
  for (int d = 1; d < 256; d <<= 1) {
    __syncthreads();
    uint32_t v = sA[t] + ((t + d < 256) ? sA[t + d] : 0u);
    __syncthreads();
    sA[t] = v;
  }
  __syncthreads();
  uint32_t nxt = (t < 255) ? sA[t + 1] : 0u;
  if (cumAbove + sA[t] >= PRE_NMS && cumAbove + nxt < PRE_NMS)
    thresh[b] = (uint32_t)((cb << 8) | t);
}

// K5: gather candidate KEYS ONLY (8B each), block-aggregated atomics: one
// atomicAdd per category per block. Strictly-above fills [0, c1); ties fill
// from CAP-1 downward; overflow ties dropped (only above 2096 ties/batch).
__global__ void k_gather(const uint32_t* __restrict__ keys,
                         const uint32_t* __restrict__ thresh,
                         uint32_t* __restrict__ cnts,
                         unsigned long long* __restrict__ cand_sort,
                         int A, int chunks) {
  int b = blockIdx.y;
  int t = threadIdx.x;  // 256
  int lane = t & 63;
  int w = t >> 6;  // wave 0..3
  __shared__ unsigned long long s_mA[MAXCHUNK * 4], s_mT[MAXCHUNK * 4];
  __shared__ uint32_t s_offA[MAXCHUNK * 4], s_offT[MAXCHUNK * 4];
  __shared__ uint32_t s_cA[MAXCHUNK * 4], s_cT[MAXCHUNK * 4];
  __shared__ uint32_t s_baseA, s_baseT;
  uint32_t beta = thresh[b];
  uint32_t kreg[MAXCHUNK];
  int base_a = blockIdx.x * (chunks * 256);
  for (int c = 0; c < chunks; c++) {
    int a = base_a + c * 256 + t;
    bool inb = a < A;
    uint32_t k = inb ? keys[(size_t)b * A + a] : KEY_NEGINF;
    kreg[c] = k;
    uint32_t bk = k >> 16;
    bool fin = (k != KEY_NEGINF);
    unsigned long long mA = __ballot(fin && (bk > beta));
    unsigned long long mT = __ballot(fin && (bk == beta));
    if (lane == 0) {
      s_mA[c * 4 + w] = mA;
      s_mT[c * 4 + w] = mT;
    }
  }
  __syncthreads();
  if (t < chunks * 4) {
    s_cA[t] = (uint32_t)__popcll(s_mA[t]);
    s_cT[t] = (uint32_t)__popcll(s_mT[t]);
  }
  __syncthreads();
  if (t == 0) {  // serial scan over <=44 entries, then ONE atomic per category
    uint32_t accA = 0, accT = 0;
    for (int id = 0; id < chunks * 4; id++) {
      s_offA[id] = accA;
      accA += s_cA[id];
      s_offT[id] = accT;
      accT += s_cT[id];
    }
    s_baseA = accA ? atomicAdd(&cnts[b * CNT_STRIDE + 0], accA) : 0u;
    s_baseT = accT ? atomicAdd(&cnts[b * CNT_STRIDE + 1], accT) : 0u;
  }
  __syncthreads();
  uint32_t baseA = s_baseA, baseT = s_baseT;
  unsigned long long lower = ((unsigned long long)1 << lane) - 1;
  for (int c = 0; c < chunks; c++) {
    int id = c * 4 + w;
    unsigned long long mA = s_mA[id], mT = s_mT[id];
    bool above = (mA >> lane) & 1;
    bool tie = (mT >> lane) & 1;
    if (!(above || tie)) continue;
    int pos;
    if (above) {
      pos = (int)(baseA + s_offA[id] + (uint32_t)__popcll(mA & lower));
      if (pos >= PRE_NMS) continue;  // defensive; cannot happen
    } else {
      pos = CAP - 1 - (int)(baseT + s_offT[id] + (uint32_t)__popcll(mT & lower));
      if (pos < PRE_NMS) continue;  // drop overflow ties
    }
    int a = base_a + c * 256 + t;
    // sort key: (score_key desc, anchor index asc) via descending u64 order
    cand_sort[(size_t)b * CAP + pos] =
        ((unsigned long long)kreg[c] << 32) | (uint32_t)(~(uint32_t)a);
  }
}

// K6a: default-fill selection (pads for degenerate batches; overwritten by
// k_rank for every live rank < SEL). grid = (SEL/256, B).
__global__ void k_fillsel(float4* __restrict__ sel_box,
                          float* __restrict__ sel_score) {
  int b = blockIdx.y;
  int r = blockIdx.x * 256 + threadIdx.x;
  sel_score[(size_t)b * SEL + r] = -INFINITY;
  sel_box[(size_t)b * SEL + r] = make_float4(0.0f, 0.0f, 0.0f, 0.0f);
}

// K6b: enumeration sort. Keys are strictly distinct ((score_key, ~anchor)),
// so rank = #{keys > mine} is the exact descending-sorted position. Each
// thread owns one slot, streams the batch's live slots through LDS broadcast
// tiles, and (if rank < SEL) decodes its box from the embedded anchor index.
// grid = (CAP/256, B). Fully parallel: 256 blocks, no cross-thread deps.
__global__ void k_rank(const unsigned long long* __restrict__ cand_sort,
                       const uint32_t* __restrict__ cnts,
                       const float4* __restrict__ anchors,
                       const float4* __restrict__ deltas,
                       float4* __restrict__ sel_box,
                       float* __restrict__ sel_score, int A) {
  int b = blockIdx.y;
  int t = threadIdx.x;  // 256
  uint32_t c1 = cnts[b * CNT_STRIDE + 0];
  if (c1 > PRE_NMS) c1 = PRE_NMS;
  uint32_t c2 = cnts[b * CNT_STRIDE + 1];
  if (c2 > CAP - PRE_NMS) c2 = CAP - PRE_NMS;
  int loTie = CAP - (int)c2;
  int bs = blockIdx.x * 256;
  if (bs >= (int)c1 && bs + 256 <= loTie) return;  // block fully in dead gap
  int s = bs + t;
  bool live = (s < (int)c1) || (s >= loTie);
  unsigned long long myKey = live ? cand_sort[(size_t)b * CAP + s] : 0ull;
  __shared__ unsigned long long tile[256];
  int rank = 0;
  for (int ts = 0; ts < CAP; ts += 256) {  // tile-skip is block-uniform
    if (ts >= (int)c1 && ts + 256 <= loTie) continue;
    int idx = ts + t;
    bool lv = (idx < (int)c1) || (idx >= loTie);
    __syncthreads();
    tile[t] = lv ? cand_sort[(size_t)b * CAP + idx] : 0ull;
    __syncthreads();
    if (live) {
#pragma unroll 8
      for (int j = 0; j < 256; j++) rank += (tile[j] > myKey) ? 1 : 0;
    }
  }
  if (live && rank < SEL) {
    uint32_t a = ~((uint32_t)myKey);
    float4 box = decode_clip(anchors[a], deltas[(size_t)b * A + a]);
    sel_score[(size_t)b * SEL + rank] = key2f((uint32_t)(myKey >> 32));
    sel_box[(size_t)b * SEL + rank] = box;
  }
}

// K7: suppression bitmask. mask[b][i][jb] bit jj set iff j = jb*64+jj > i,
// j < PRE_NMS, IoU(box_i, box_j) > NMS_THR. Rows in [PRE_NMS, SEL) zeroed
// so k_scanout never reads unwritten workspace.
__global__ void k_nmsmask(const float4* __restrict__ sel_box,
                          unsigned long long* __restrict__ mask) {
  int jb = blockIdx.x;  // col block
  int ib = blockIdx.y;  // row block
  int b = blockIdx.z;
  int t = threadIdx.x;  // 64
  int i = ib * 64 + t;
  if (jb < ib) {  // uniform per block; entire col tile is <= all rows
    mask[((size_t)b * SEL + i) * NW + jb] = 0ull;
    return;
  }
  __shared__ float4 cb[64];
  __shared__ float careb[64];
  int j0 = jb * 64;
  float4 cbx = sel_box[(size_t)b * SEL + j0 + t];
  cb[t] = cbx;
  careb[t] = (cbx.z - cbx.x) * (cbx.w - cbx.y);
  __syncthreads();
  if (i >= PRE_NMS) {  // pad rows: write zeros, never leave stale poison
    mask[((size_t)b * SEL + i) * NW + jb] = 0ull;
    return;
  }
  float4 a = sel_box[(size_t)b * SEL + i];
  float area_a = (a.z - a.x) * (a.w - a.y);
  unsigned long long bits = 0ull;
  int jmax = min(64, PRE_NMS - j0);
  for (int jj = 0; jj < jmax; jj++) {
    int j = j0 + jj;
    if (j <= i) continue;
    float4 bb = cb[jj];
    float ltx = fmaxf(a.x, bb.x), lty = fmaxf(a.y, bb.y);
    float rbx = fminf(a.z, bb.z), rby = fminf(a.w, bb.w);
    float w = fmaxf(rbx - ltx, 0.0f), hgt = fmaxf(rby - lty, 0.0f);
    float inter = w * hgt;
    float iou = inter / (area_a + careb[jj] - inter + 1e-6f);
    if (iou > NMS_THR) bits |= (1ull << jj);
  }
  mask[((size_t)b * SEL + i) * NW + jb] = bits;
}

// K8: one wave per batch. Serial greedy scan over EXACTLY PRE_NMS rows.
// removed word w in lane w's register; rows prefetched 16-at-a-time into
// registers (double-buffered).
// R7: the per-kept-row serial chain no longer contains ANY readlane:
//  - each row's current-chunk mask word is broadcast up-front per 16-row
//    group (16 independent readlane_u64 -> SGPRs), and curw |= bmw[j]
//    replaces the old removed-re-broadcast (algebraically identical);
//  - row score validity comes from ONE __ballot per 64-row chunk instead of
//    a readlane per kept row.
// All scan branches are wave-uniform (curw/vb/kc uniform); only the t==0
// keptList store touches the exec mask.
__global__ void k_scanout(const float4* __restrict__ sel_box,
                          const float* __restrict__ sel_score,
                          const unsigned long long* __restrict__ mask,
                          float* __restrict__ out) {
  int b = blockIdx.x;
  int t = threadIdx.x;  // 64 = 1 wave
  int tw = t & 31;
  __shared__ uint32_t keptList[POST_NMS];
  unsigned long long removed = 0ull;  // lane w<32 owns word w (dup in w+32)
  int kc = 0;
  const unsigned long long* mbase = mask + (size_t)b * SEL * NW;
  for (int chunk = 0; chunk < SEL / 64; chunk++) {
    int rmax = PRE_NMS - chunk * 64;  // rows beyond PRE_NMS excluded
    if (rmax <= 0) break;
    if (rmax > 64) rmax = 64;
    uint32_t scb_all =
        __float_as_uint(sel_score[(size_t)b * SEL + chunk * 64 + t]);
    // validity of all 64 rows of this chunk in one wave op (uniform u64)
    unsigned long long vb = __ballot(scb_all != 0xFF800000u);
    const unsigned long long* cbase = mbase + (size_t)chunk * 64 * NW;
    unsigned long long curw = readlane_u64(removed, chunk);
    unsigned long long m[16], mn[16];
#pragma unroll
    for (int j = 0; j < 16; j++) m[j] = cbase[j * NW + tw];
    for (int sub = 0; sub < 4; sub++) {
      if (sub < 3) {
#pragma unroll
        for (int j = 0; j < 16; j++)
          mn[j] = cbase[((sub + 1) * 16 + j) * NW + tw];
      }
      // Broadcast each row's current-chunk word once; these 16 readlane_u64
      // are independent of the serial scan below (land in SGPRs, pipelined).
      unsigned long long bmw[16];
#pragma unroll
      for (int j = 0; j < 16; j++) bmw[j] = readlane_u64(m[j], chunk);
#pragma unroll
      for (int j = 0; j < 16; j++) {
        int r = sub * 16 + j;
        if (r < rmax && !((curw >> r) & 1ull)) {
          curw |= bmw[j];     // == old readlane(removed|m[j], chunk)
          removed |= m[j];    // per-lane, off the serial chain
          if ((vb >> r) & 1ull) {  // score != -inf
            if (t == 0) keptList[kc] = (uint32_t)(chunk * 64 + r);
            kc++;
            if (kc == POST_NMS) goto writeout;
          }
        }
      }
      if (sub < 3) {
#pragma unroll
        for (int j = 0; j < 16; j++) m[j] = mn[j];
      }
    }
  }
writeout:
  __syncthreads();
  for (int r = t; r < POST_NMS; r += 64) {
    float4 bx = make_float4(0.0f, 0.0f, 0.0f, 0.0f);
    float sc = 0.0f;
    if (r < kc) {
      int i = (int)keptList[r];
      bx = sel_box[(size_t)b * SEL + i];
      sc = sel_score[(size_t)b * SEL + i];
    }
    float* o = out + ((size_t)b * POST_NMS + r) * 5;
    o[0] = bx.x;
    o[1] = bx.y;
    o[2] = bx.z;
    o[3] = bx.w;
    o[4] = sc;
  }
}

extern "C" void kernel_launch(void* const* d_in, const int* in_sizes, int n_in,
                              void* d_out, int out_size, void* d_ws, size_t ws_size,
                              hipStream_t stream) {
  const float* anchors = (const float*)d_in[0];  // (A, 4)
  const float* deltas = (const float*)d_in[1];   // (B, A, 4)
  const float* scores = (const float*)d_in[2];   // (B, A)
  int A = in_sizes[0] / 4;
  int BA = in_sizes[2];
  int B = BA / A;
  float* out = (float*)d_out;

  char* ws = (char*)d_ws;
  size_t off = 0;
  uint32_t* keys = (uint32_t*)(ws + off);
  off += (size_t)BA * 4;
  uint32_t* chist = (uint32_t*)(ws + off);
  off += (size_t)B * 256 * 4;
  uint32_t* fhist = (uint32_t*)(ws + off);
  off += (size_t)B * 256 * 4;
  int* cbArr = (int*)(ws + off);
  off += (size_t)B * 4;
  uint32_t* cumArr = (uint32_t*)(ws + off);
  off += (size_t)B * 4;
  uint32_t* thresh = (uint32_t*)(ws + off);
  off += (size_t)B * 4;
  off = (off + 127) & ~(size_t)127;
  uint32_t* cnts = (uint32_t*)(ws + off);
  off += (size_t)B * CNT_STRIDE * 4;
  off = (off + 15) & ~(size_t)15;
  unsigned long long* cand_sort = (unsigned long long*)(ws + off);
  off += (size_t)B * CAP * 8;
  float4* sel_box = (float4*)(ws + off);
  off += (size_t)B * SEL * 16;
  float* sel_score = (float*)(ws + off);
  off += (size_t)B * SEL * 4;
  unsigned long long* mask = (unsigned long long*)(ws + off);
  off += (size_t)B * SEL * NW * 8;
  // total ~27 MB

  // Block geometry for per-batch streaming kernels: A = 261888 = 256*11*93.
  int chunks = (A % (256 * 11) == 0) ? 11 : 1;
  int bpb = (A + 256 * chunks - 1) / (256 * chunks);  // blocks per batch

  hipMemsetAsync(chist, 0, (size_t)B * 256 * 4 * 2, stream);  // chist+fhist
  k_decode<<<dim3(bpb, B), 256, 0, stream>>>((const float4*)anchors,
                                             (const float4*)deltas, scores,
                                             keys, chist, A, chunks);
  k_coarse<<<B, 256, 0, stream>>>(chist, cbArr, cumArr);
  k_fine<<<dim3(bpb, B), 256, 0, stream>>>(keys, cbArr, fhist, A, chunks);
  k_thresh<<<B, 256, 0, stream>>>(fhist, cbArr, cumArr, thresh, cnts);
  k_gather<<<dim3(bpb, B), 256, 0, stream>>>(keys, thresh, cnts, cand_sort, A,
                                             chunks);
  k_fillsel<<<dim3(SEL / 256, B), 256, 0, stream>>>(sel_box, sel_score);
  k_rank<<<dim3(CAP / 256, B), 256, 0, stream>>>(cand_sort, cnts,
                                                 (const float4*)anchors,
                                                 (const float4*)deltas,
                                                 sel_box, sel_score, A);
  k_nmsmask<<<dim3(NW, SEL / 64, B), 64, 0, stream>>>(sel_box, mask);
  k_scanout<<<B, 64, 0, stream>>>(sel_box, sel_score, mask, out);
}

// Round 2
// 329.285 us; speedup vs baseline: 1.1503x; 1.1503x over previous
//
#include <hip/hip_runtime.h>
#include <stdint.h>
#include <math.h>

// RPN proposal filtering: decode -> clip -> validity mask -> stable top-2000
// -> greedy NMS (IoU > 0.7) -> first 1000 kept -> (B, 1000, 5).
//
// R8: k_scanout rewritten as an ffs-driven alive-only scan. R7's eager
// broadcast regressed (91->125us) because it paid 32 v_readlane per 16 rows
// unconditionally; suppressed rows must cost ZERO. Now:
//  - work = ~curw & range; serial loop visits only set bits via ffs;
//    per kept row: readlane(diag, r) + s_or/andn2 (~20 cyc), suppressed rows
//    are cleared from work in bulk and never visited.
//  - keptList append + kc are batch-computed per chunk from keptbits
//    (popcount rank, lane-parallel) - off the serial chain.
//  - full-row removed|= accumulation: 64 row-words preloaded to registers
//    before the scan (latency hidden under it), OR'd after the scan under
//    wave-uniform branches on keptbits (skipped rows = 1 scalar branch).

#define IMGF 1024.0f
#define PRE_NMS 2000
#define POST_NMS 1000
#define NMS_THR 0.7f
#define MIN_SZ 16.0f
#define CAP 4096          // candidate buffer per batch
#define SEL 2048          // padded selection stride (>= PRE_NMS)
#define NW (SEL / 64)     // 32 mask words per row
#define CNT_STRIDE 32     // u32s per batch for counters (128 B -> own line)
#define KEY_NEGINF 0x007FFFFFu  // f2key(-inf)
#define MAXCHUNK 12

// Order-preserving float -> u32 key (all floats incl. -inf totally ordered).
__device__ __forceinline__ uint32_t f2key(float f) {
  uint32_t u = __float_as_uint(f);
  return (u & 0x80000000u) ? ~u : (u | 0x80000000u);
}
__device__ __forceinline__ float key2f(uint32_t k) {
  uint32_t u = (k & 0x80000000u) ? (k & 0x7FFFFFFFu) : ~k;
  return __uint_as_float(u);
}

__device__ __forceinline__ unsigned long long readlane_u64(unsigned long long v,
                                                           int lane) {
  unsigned int lo = __builtin_amdgcn_readlane((unsigned int)v, lane);
  unsigned int hi = __builtin_amdgcn_readlane((unsigned int)(v >> 32), lane);
  return ((unsigned long long)hi << 32) | lo;
}

// Mirrors reference _decode + clip, fp32.
__device__ __forceinline__ float4 decode_clip(float4 anc, float4 dlt) {
  float aw = anc.z - anc.x;
  float ah = anc.w - anc.y;
  float ax = anc.x + 0.5f * aw;
  float ay = anc.y + 0.5f * ah;
  float dw = fminf(dlt.z, 4.0f);
  float dh = fminf(dlt.w, 4.0f);
  float px = dlt.x * aw + ax;
  float py = dlt.y * ah + ay;
  float pw = expf(dw) * aw;
  float ph = expf(dh) * ah;
  float x1 = px - 0.5f * pw, y1 = py - 0.5f * ph;
  float x2 = px + 0.5f * pw, y2 = py + 0.5f * ph;
  x1 = fminf(fmaxf(x1, 0.0f), IMGF);
  y1 = fminf(fmaxf(y1, 0.0f), IMGF);
  x2 = fminf(fmaxf(x2, 0.0f), IMGF);
  y2 = fminf(fmaxf(y2, 0.0f), IMGF);
  return make_float4(x1, y1, x2, y2);
}

// K1: decode -> masked-score key; per-block LDS coarse hist of key>>24
// (finite keys only), ballot-match wave aggregation, one aggregated global
// flush per block. grid = (bpb, B).
__global__ void k_decode(const float4* __restrict__ anchors,
                         const float4* __restrict__ deltas,
                         const float* __restrict__ scores,
                         uint32_t* __restrict__ keys,
                         uint32_t* __restrict__ chist,
                         int A, int chunks) {
  int b = blockIdx.y;
  int t = threadIdx.x;  // 256
  int lane = t & 63;
  __shared__ uint32_t shist[256];
  shist[t] = 0;
  __syncthreads();
  int base_a = blockIdx.x * (chunks * 256);
  for (int c = 0; c < chunks; c++) {
    int a = base_a + c * 256 + t;
    bool inb = a < A;
    int ac = inb ? a : (A - 1);
    size_t i = (size_t)b * A + ac;
    float4 box = decode_clip(anchors[ac], deltas[i]);
    bool valid = (box.z - box.x >= MIN_SZ) && (box.w - box.y >= MIN_SZ);
    float ms = valid ? scores[i] : -INFINITY;
    uint32_t k = f2key(ms);
    if (inb) keys[i] = k;
    uint32_t bucket = k >> 24;
    bool fin = inb && (k != KEY_NEGINF);
    // lanes with equal bucket -> one LDS atomic by the leader
    unsigned long long match = __ballot(fin);
#pragma unroll
    for (int bit = 0; bit < 8; bit++) {
      bool hb = (bucket >> bit) & 1;
      unsigned long long bb = __ballot(hb && fin);
      match &= hb ? bb : ~bb;
    }
    if (fin && (__ffsll((long long)match) - 1 == lane))
      atomicAdd(&shist[bucket], (uint32_t)__popcll(match));
  }
  __syncthreads();
  uint32_t v = shist[t];
  if (v) atomicAdd(&chist[b * 256 + t], v);
}

// K2: pick coarse bucket cb s.t. countAbove(cb) < PRE_NMS <= countAbove(cb)+chist[cb].
__global__ void k_coarse(const uint32_t* __restrict__ chist,
                         int* __restrict__ cbArr,
                         uint32_t* __restrict__ cumArr) {
  int b = blockIdx.x;
  int t = threadIdx.x;  // 256
  __shared__ uint32_t sA[256];
  sA[t] = chist[b * 256 + t];
  for (int d = 1; d < 256; d <<= 1) {  // inclusive suffix scan
    __syncthreads();
    uint32_t v = sA[t] + ((t + d < 256) ? sA[t + d] : 0u);
    __syncthreads();
    sA[t] = v;
  }
  __syncthreads();
  if (t == 0 && sA[0] < PRE_NMS) {  // degenerate: < PRE_NMS finite entries
    cbArr[b] = -1;
    cumArr[b] = 0;
  }
  uint32_t nxt = (t < 255) ? sA[t + 1] : 0u;
  if (sA[t] >= PRE_NMS && nxt < PRE_NMS) {
    cbArr[b] = t;
    cumArr[b] = nxt;  // count strictly above coarse bucket t
  }
}

// K3: fine hist of key bits[23:16] for elements whose coarse bucket == cb[b].
__global__ void k_fine(const uint32_t* __restrict__ keys,
                       const int* __restrict__ cbArr,
                       uint32_t* __restrict__ fhist,
                       int A, int chunks) {
  int b = blockIdx.y;
  int t = threadIdx.x;  // 256
  int cb = cbArr[b];
  if (cb < 0) return;
  __shared__ uint32_t shist[256];
  shist[t] = 0;
  __syncthreads();
  int base_a = blockIdx.x * (chunks * 256);
  uint32_t cbu = (uint32_t)cb;
  for (int c = 0; c < chunks; c++) {
    int a = base_a + c * 256 + t;
    if (a >= A) break;
    uint32_t k = keys[(size_t)b * A + a];
    if ((k >> 24) == cbu && k != KEY_NEGINF)
      atomicAdd(&shist[(k >> 16) & 0xFFu], 1u);
  }
  __syncthreads();
  uint32_t v = shist[t];
  if (v) atomicAdd(&fhist[b * 256 + t], v);
}

// K4: final 16-bit threshold beta = (cb<<8)|d:
// count(key>>16 > beta) < PRE_NMS <= count(key>>16 >= beta), finite keys only.
__global__ void k_thresh(const uint32_t* __restrict__ fhist,
                         const int* __restrict__ cbArr,
                         const uint32_t* __restrict__ cumArr,
                         uint32_t* __restrict__ thresh,
                         uint32_t* __restrict__ cnts) {
  int b = blockIdx.x;
  int t = threadIdx.x;  // 256
  __shared__ uint32_t sA[256];
  if (t < 2) cnts[b * CNT_STRIDE + t] = 0;
  int cb = cbArr[b];
  if (cb < 0) {
    if (t == 0) thresh[b] = 0u;
    return;
  }
  uint32_t cumAbove = cumArr[b];
  sA[t] = fhist[b * 256 + t];
  for (int d = 1; d < 256; d <<= 1) {
    __syncthreads();
    uint32_t v = sA[t] + ((t + d < 256) ? sA[t + d] : 0u);
    __syncthreads();
    sA[t] = v;
  }
  __syncthreads();
  uint32_t nxt = (t < 255) ? sA[t + 1] : 0u;
  if (cumAbove + sA[t] >= PRE_NMS && cumAbove + nxt < PRE_NMS)
    thresh[b] = (uint32_t)((cb << 8) | t);
}

// K5: gather candidate KEYS ONLY (8B each), block-aggregated atomics: one
// atomicAdd per category per block. Strictly-above fills [0, c1); ties fill
// from CAP-1 downward; overflow ties dropped (only above 2096 ties/batch).
__global__ void k_gather(const uint32_t* __restrict__ keys,
                         const uint32_t* __restrict__ thresh,
                         uint32_t* __restrict__ cnts,
                         unsigned long long* __restrict__ cand_sort,
                         int A, int chunks) {
  int b = blockIdx.y;
  int t = threadIdx.x;  // 256
  int lane = t & 63;
  int w = t >> 6;  // wave 0..3
  __shared__ unsigned long long s_mA[MAXCHUNK * 4], s_mT[MAXCHUNK * 4];
  __shared__ uint32_t s_offA[MAXCHUNK * 4], s_offT[MAXCHUNK * 4];
  __shared__ uint32_t s_cA[MAXCHUNK * 4], s_cT[MAXCHUNK * 4];
  __shared__ uint32_t s_baseA, s_baseT;
  uint32_t beta = thresh[b];
  uint32_t kreg[MAXCHUNK];
  int base_a = blockIdx.x * (chunks * 256);
  for (int c = 0; c < chunks; c++) {
    int a = base_a + c * 256 + t;
    bool inb = a < A;
    uint32_t k = inb ? keys[(size_t)b * A + a] : KEY_NEGINF;
    kreg[c] = k;
    uint32_t bk = k >> 16;
    bool fin = (k != KEY_NEGINF);
    unsigned long long mA = __ballot(fin && (bk > beta));
    unsigned long long mT = __ballot(fin && (bk == beta));
    if (lane == 0) {
      s_mA[c * 4 + w] = mA;
      s_mT[c * 4 + w] = mT;
    }
  }
  __syncthreads();
  if (t < chunks * 4) {
    s_cA[t] = (uint32_t)__popcll(s_mA[t]);
    s_cT[t] = (uint32_t)__popcll(s_mT[t]);
  }
  __syncthreads();
  if (t == 0) {  // serial scan over <=44 entries, then ONE atomic per category
    uint32_t accA = 0, accT = 0;
    for (int id = 0; id < chunks * 4; id++) {
      s_offA[id] = accA;
      accA += s_cA[id];
      s_offT[id] = accT;
      accT += s_cT[id];
    }
    s_baseA = accA ? atomicAdd(&cnts[b * CNT_STRIDE + 0], accA) : 0u;
    s_baseT = accT ? atomicAdd(&cnts[b * CNT_STRIDE + 1], accT) : 0u;
  }
  __syncthreads();
  uint32_t baseA = s_baseA, baseT = s_baseT;
  unsigned long long lower = ((unsigned long long)1 << lane) - 1;
  for (int c = 0; c < chunks; c++) {
    int id = c * 4 + w;
    unsigned long long mA = s_mA[id], mT = s_mT[id];
    bool above = (mA >> lane) & 1;
    bool tie = (mT >> lane) & 1;
    if (!(above || tie)) continue;
    int pos;
    if (above) {
      pos = (int)(baseA + s_offA[id] + (uint32_t)__popcll(mA & lower));
      if (pos >= PRE_NMS) continue;  // defensive; cannot happen
    } else {
      pos = CAP - 1 - (int)(baseT + s_offT[id] + (uint32_t)__popcll(mT & lower));
      if (pos < PRE_NMS) continue;  // drop overflow ties
    }
    int a = base_a + c * 256 + t;
    // sort key: (score_key desc, anchor index asc) via descending u64 order
    cand_sort[(size_t)b * CAP + pos] =
        ((unsigned long long)kreg[c] << 32) | (uint32_t)(~(uint32_t)a);
  }
}

// K6a: default-fill selection (pads for degenerate batches; overwritten by
// k_rank for every live rank < SEL). grid = (SEL/256, B).
__global__ void k_fillsel(float4* __restrict__ sel_box,
                          float* __restrict__ sel_score) {
  int b = blockIdx.y;
  int r = blockIdx.x * 256 + threadIdx.x;
  sel_score[(size_t)b * SEL + r] = -INFINITY;
  sel_box[(size_t)b * SEL + r] = make_float4(0.0f, 0.0f, 0.0f, 0.0f);
}

// K6b: enumeration sort. Keys are strictly distinct ((score_key, ~anchor)),
// so rank = #{keys > mine} is the exact descending-sorted position. Each
// thread owns one slot, streams the batch's live slots through LDS broadcast
// tiles, and (if rank < SEL) decodes its box from the embedded anchor index.
// grid = (CAP/256, B). Fully parallel: 256 blocks, no cross-thread deps.
__global__ void k_rank(const unsigned long long* __restrict__ cand_sort,
                       const uint32_t* __restrict__ cnts,
                       const float4* __restrict__ anchors,
                       const float4* __restrict__ deltas,
                       float4* __restrict__ sel_box,
                       float* __restrict__ sel_score, int A) {
  int b = blockIdx.y;
  int t = threadIdx.x;  // 256
  uint32_t c1 = cnts[b * CNT_STRIDE + 0];
  if (c1 > PRE_NMS) c1 = PRE_NMS;
  uint32_t c2 = cnts[b * CNT_STRIDE + 1];
  if (c2 > CAP - PRE_NMS) c2 = CAP - PRE_NMS;
  int loTie = CAP - (int)c2;
  int bs = blockIdx.x * 256;
  if (bs >= (int)c1 && bs + 256 <= loTie) return;  // block fully in dead gap
  int s = bs + t;
  bool live = (s < (int)c1) || (s >= loTie);
  unsigned long long myKey = live ? cand_sort[(size_t)b * CAP + s] : 0ull;
  __shared__ unsigned long long tile[256];
  int rank = 0;
  for (int ts = 0; ts < CAP; ts += 256) {  // tile-skip is block-uniform
    if (ts >= (int)c1 && ts + 256 <= loTie) continue;
    int idx = ts + t;
    bool lv = (idx < (int)c1) || (idx >= loTie);
    __syncthreads();
    tile[t] = lv ? cand_sort[(size_t)b * CAP + idx] : 0ull;
    __syncthreads();
    if (live) {
#pragma unroll 8
      for (int j = 0; j < 256; j++) rank += (tile[j] > myKey) ? 1 : 0;
    }
  }
  if (live && rank < SEL) {
    uint32_t a = ~((uint32_t)myKey);
    float4 box = decode_clip(anchors[a], deltas[(size_t)b * A + a]);
    sel_score[(size_t)b * SEL + rank] = key2f((uint32_t)(myKey >> 32));
    sel_box[(size_t)b * SEL + rank] = box;
  }
}

// K7: suppression bitmask. mask[b][i][jb] bit jj set iff j = jb*64+jj > i,
// j < PRE_NMS, IoU(box_i, box_j) > NMS_THR. Rows in [PRE_NMS, SEL) zeroed
// so k_scanout never reads unwritten workspace.
__global__ void k_nmsmask(const float4* __restrict__ sel_box,
                          unsigned long long* __restrict__ mask) {
  int jb = blockIdx.x;  // col block
  int ib = blockIdx.y;  // row block
  int b = blockIdx.z;
  int t = threadIdx.x;  // 64
  int i = ib * 64 + t;
  if (jb < ib) {  // uniform per block; entire col tile is <= all rows
    mask[((size_t)b * SEL + i) * NW + jb] = 0ull;
    return;
  }
  __shared__ float4 cb[64];
  __shared__ float careb[64];
  int j0 = jb * 64;
  float4 cbx = sel_box[(size_t)b * SEL + j0 + t];
  cb[t] = cbx;
  careb[t] = (cbx.z - cbx.x) * (cbx.w - cbx.y);
  __syncthreads();
  if (i >= PRE_NMS) {  // pad rows: write zeros, never leave stale poison
    mask[((size_t)b * SEL + i) * NW + jb] = 0ull;
    return;
  }
  float4 a = sel_box[(size_t)b * SEL + i];
  float area_a = (a.z - a.x) * (a.w - a.y);
  unsigned long long bits = 0ull;
  int jmax = min(64, PRE_NMS - j0);
  for (int jj = 0; jj < jmax; jj++) {
    int j = j0 + jj;
    if (j <= i) continue;
    float4 bb = cb[jj];
    float ltx = fmaxf(a.x, bb.x), lty = fmaxf(a.y, bb.y);
    float rbx = fminf(a.z, bb.z), rby = fminf(a.w, bb.w);
    float w = fmaxf(rbx - ltx, 0.0f), hgt = fmaxf(rby - lty, 0.0f);
    float inter = w * hgt;
    float iou = inter / (area_a + careb[jj] - inter + 1e-6f);
    if (iou > NMS_THR) bits |= (1ull << jj);
  }
  mask[((size_t)b * SEL + i) * NW + jb] = bits;
}

// K8: one wave per batch. ffs-driven greedy scan: only ALIVE rows are
// visited. Per chunk of 64 rows:
//   diag  = per-lane current-chunk word of each row (lane r owns row r)
//   curw  = removed word for this chunk at entry (readlane of distributed
//           removed state)
//   work  = ~curw & range; loop: r=ffs(work); curw|=readlane(diag,r);
//           work &= ~(curw|bits<=r). Suppressed rows never visited.
//   keptbits -> lane-parallel keptList append (popcount rank) + kc update.
//   removed |= mask rows of kept rows: 64 row-words PRELOADED into regs
//   before the scan (latency hidden), OR'd under wave-uniform branches.
__global__ void __launch_bounds__(64, 1)
k_scanout(const float4* __restrict__ sel_box,
          const float* __restrict__ sel_score,
          const unsigned long long* __restrict__ mask,
          float* __restrict__ out) {
  int b = blockIdx.x;
  int t = threadIdx.x;  // 64 = 1 wave
  int tw = t & 31;
  __shared__ uint32_t keptList[POST_NMS + 64];  // overshoot space
  unsigned long long removed = 0ull;  // lane w<32 owns word w (dup in w+32)
  int kc = 0;
  const unsigned long long* mbase = mask + (size_t)b * SEL * NW;
  const int lastChunk = (PRE_NMS - 1) / 64;  // 31
  for (int chunk = 0; chunk <= lastChunk; chunk++) {
    int rmax = PRE_NMS - chunk * 64;  // rows beyond PRE_NMS excluded
    if (rmax > 64) rmax = 64;
    // per-lane diag word: row (chunk*64 + t), word index = chunk
    unsigned long long diag = mbase[((size_t)(chunk * 64 + t)) * NW + chunk];
    // preload all 64 row-words of this chunk (word tw per lane); consumed
    // only AFTER the serial scan -> latency fully hidden under it.
    const unsigned long long* cbase = mbase + (size_t)chunk * 64 * NW;
    unsigned long long m[64];
#pragma unroll
    for (int j = 0; j < 64; j++) m[j] = cbase[j * NW + tw];
    // score validity for all 64 rows in one ballot
    uint32_t scb =
        __float_as_uint(sel_score[(size_t)b * SEL + chunk * 64 + t]);
    unsigned long long vb = __ballot(scb != 0xFF800000u);
    // entry removed word for this chunk
    unsigned long long curw = readlane_u64(removed, chunk);
    unsigned long long range =
        (rmax >= 64) ? ~0ull : ((1ull << rmax) - 1ull);
    unsigned long long work = ~curw & range;
    unsigned long long keptbits = 0ull;
    while (work) {
      int r = __ffsll((long long)work) - 1;
      keptbits |= (1ull << r);
      unsigned long long d = readlane_u64(diag, r);
      curw |= d;
      unsigned long long low = (2ull << r) - 1ull;  // bits 0..r (r=63 ok)
      work &= ~(curw | low);
    }
    // bookkeeping (off the serial chain)
    unsigned long long kv = keptbits & vb;
    if ((kv >> t) & 1ull) {
      int rank = (int)__popcll(kv & ((1ull << t) - 1ull));
      keptList[kc + rank] = (uint32_t)(chunk * 64 + t);
    }
    kc += (int)__popcll(kv);
    if (kc >= POST_NMS) break;           // future chunks irrelevant
    if (chunk == lastChunk) break;       // no future chunks
    // accumulate removed state: wave-uniform branch per row, regs only
#pragma unroll
    for (int j = 0; j < 64; j++) {
      if ((keptbits >> j) & 1ull) removed |= m[j];
    }
  }
  int kcc = kc < POST_NMS ? kc : POST_NMS;
  __syncthreads();
  for (int r = t; r < POST_NMS; r += 64) {
    float4 bx = make_float4(0.0f, 0.0f, 0.0f, 0.0f);
    float sc = 0.0f;
    if (r < kcc) {
      int i = (int)keptList[r];
      bx = sel_box[(size_t)b * SEL + i];
      sc = sel_score[(size_t)b * SEL + i];
    }
    float* o = out + ((size_t)b * POST_NMS + r) * 5;
    o[0] = bx.x;
    o[1] = bx.y;
    o[2] = bx.z;
    o[3] = bx.w;
    o[4] = sc;
  }
}

extern "C" void kernel_launch(void* const* d_in, const int* in_sizes, int n_in,
                              void* d_out, int out_size, void* d_ws, size_t ws_size,
                              hipStream_t stream) {
  const float* anchors = (const float*)d_in[0];  // (A, 4)
  const float* deltas = (const float*)d_in[1];   // (B, A, 4)
  const float* scores = (const float*)d_in[2];   // (B, A)
  int A = in_sizes[0] / 4;
  int BA = in_sizes[2];
  int B = BA / A;
  float* out = (float*)d_out;

  char* ws = (char*)d_ws;
  size_t off = 0;
  uint32_t* keys = (uint32_t*)(ws + off);
  off += (size_t)BA * 4;
  uint32_t* chist = (uint32_t*)(ws + off);
  off += (size_t)B * 256 * 4;
  uint32_t* fhist = (uint32_t*)(ws + off);
  off += (size_t)B * 256 * 4;
  int* cbArr = (int*)(ws + off);
  off += (size_t)B * 4;
  uint32_t* cumArr = (uint32_t*)(ws + off);
  off += (size_t)B * 4;
  uint32_t* thresh = (uint32_t*)(ws + off);
  off += (size_t)B * 4;
  off = (off + 127) & ~(size_t)127;
  uint32_t* cnts = (uint32_t*)(ws + off);
  off += (size_t)B * CNT_STRIDE * 4;
  off = (off + 15) & ~(size_t)15;
  unsigned long long* cand_sort = (unsigned long long*)(ws + off);
  off += (size_t)B * CAP * 8;
  float4* sel_box = (float4*)(ws + off);
  off += (size_t)B * SEL * 16;
  float* sel_score = (float*)(ws + off);
  off += (size_t)B * SEL * 4;
  unsigned long long* mask = (unsigned long long*)(ws + off);
  off += (size_t)B * SEL * NW * 8;
  // total ~27 MB

  // Block geometry for per-batch streaming kernels: A = 261888 = 256*11*93.
  int chunks = (A % (256 * 11) == 0) ? 11 : 1;
  int bpb = (A + 256 * chunks - 1) / (256 * chunks);  // blocks per batch

  hipMemsetAsync(chist, 0, (size_t)B * 256 * 4 * 2, stream);  // chist+fhist
  k_decode<<<dim3(bpb, B), 256, 0, stream>>>((const float4*)anchors,
                                             (const float4*)deltas, scores,
                                             keys, chist, A, chunks);
  k_coarse<<<B, 256, 0, stream>>>(chist, cbArr, cumArr);
  k_fine<<<dim3(bpb, B), 256, 0, stream>>>(keys, cbArr, fhist, A, chunks);
  k_thresh<<<B, 256, 0, stream>>>(fhist, cbArr, cumArr, thresh, cnts);
  k_gather<<<dim3(bpb, B), 256, 0, stream>>>(keys, thresh, cnts, cand_sort, A,
                                             chunks);
  k_fillsel<<<dim3(SEL / 256, B), 256, 0, stream>>>(sel_box, sel_score);
  k_rank<<<dim3(CAP / 256, B), 256, 0, stream>>>(cand_sort, cnts,
                                                 (const float4*)anchors,
                                                 (const float4*)deltas,
                                                 sel_box, sel_score, A);
  k_nmsmask<<<dim3(NW, SEL / 64, B), 64, 0, stream>>>(sel_box, mask);
  k_scanout<<<B, 64, 0, stream>>>(sel_box, sel_score, mask, out);
}